// Round 7
// baseline (254.633 us; speedup 1.0000x reference)
//
#include <hip/hip_runtime.h>
#include <hip/hip_bf16.h>

typedef __hip_bfloat16 bf16;
typedef __attribute__((ext_vector_type(8))) short s8v;   // 8 x bf16 (4 VGPRs)
typedef __attribute__((ext_vector_type(4))) float f4v;   // MFMA accumulator

#define LOG2E 1.44269504088896340736f
#define CSCALE (0.125f * LOG2E)          // fold 1/sqrt(64) and log2e
#define MASK_B2 (-14426.950408889634f)   // -10000 * LOG2E (log2-domain bias)

#define BB 2
#define LL 2048
#define DD 1024
#define HH 16
#define HD 64
#define MTOT 4096
#define PER_T 4194304  // B*H*L*HD elements (8 MiB bf16)

struct alignas(8) B4 { bf16 v[4]; };

// async global->LDS 16B: data lands at lds_base + lane*16 (base wave-uniform)
__device__ __forceinline__ void async_cp16(const bf16* g, bf16* l) {
    __builtin_amdgcn_global_load_lds(
        (const __attribute__((address_space(1))) void*)g,
        (__attribute__((address_space(3))) void*)l, 16, 0, 0);
}

// ---------------------------------------------------------------------------
// f32 -> bf16 bulk conversion -- WEIGHTS ONLY now (4 x 1024x1024 = 24 MB
// traffic). Activations are converted in-flight by the QKV GEMM A-staging.
// ---------------------------------------------------------------------------
struct CvtArgs {
    const float* src[4];
    bf16* dst[4];
    int n[4];
};

__global__ __launch_bounds__(256) void cvt_kernel(CvtArgs args) {
    const int which = blockIdx.y;
    const float* __restrict__ src = args.src[which];
    bf16* __restrict__ dst = args.dst[which];
    const int n4 = args.n[which] >> 2;
    const int stride = gridDim.x * 256;
    for (int i = blockIdx.x * 256 + threadIdx.x; i < n4; i += stride) {
        const float4 f = ((const float4*)src)[i];
        B4 o;
        o.v[0] = __float2bfloat16(f.x);
        o.v[1] = __float2bfloat16(f.y);
        o.v[2] = __float2bfloat16(f.z);
        o.v[3] = __float2bfloat16(f.w);
        ((B4*)dst)[i] = o;
    }
}

// ---------------------------------------------------------------------------
// m97-style GEMM: C[m,n] = A[m,:].W[n,:] + bias[n]; 128x128 tile, BK=64,
// single-buffered LDS (2-barrier K-loop), XOR swizzle.
//   AF32=1 (QKV proj): A is the ORIGINAL f32 activation tensor. A-staging is
//     reg-staged: per 8-row group, each lane loads 2 coalesced float4 (rows
//     li>>4 / 4+(li>>4), f32 cols (li&15)*4), converts via __float2bfloat16
//     (bit-identical to the old cvt kernel), and ds_writes 8B to the
//     swizzled LDS slot (source chunk c of row r lands at position c^(r&7),
//     exactly the layout the fragment readers expect). B stays DMA.
//   AF32=0 (O proj): A bf16 via global_load_lds as before.
//   SWAP=1 (Q/K proj, O proj): mfma(b,a) -> lane holds 4 consecutive n.
//     O proj: direct float4 stores (no LDS). Q/K: bf16 via LDS [m][136].
//   SWAP=0 (V proj, transposed output): mfma(a,b) -> 4 consecutive m;
//     LDS [n][136], read back 8 consecutive l -> 16B stores along l.
// ---------------------------------------------------------------------------
struct QkvArgs {
    const float* A[3];
    const bf16* W[3];
    const float* bias[3];
    bf16* out[3];
};

template <int FUSED, int SWAP, int AF32>
__device__ __forceinline__ void gemm_body(const void* Aptr,
                                          const bf16* __restrict__ W,
                                          const float* __restrict__ bias,
                                          bf16* __restrict__ out_bf,
                                          float* __restrict__ out_f,
                                          float gatef, char* smem) {
    bf16* sA = (bf16*)smem;                    // 16 KB
    bf16* sB = (bf16*)(smem + 128 * 64 * 2);   // 16 KB
    bf16* sE = (bf16*)smem;                    // epilogue transpose, 34 KB

    const bf16* __restrict__ Ab = (const bf16*)Aptr;
    const float* __restrict__ Af = (const float*)Aptr;

    const int lane = threadIdx.x & 63;
    const int w = threadIdx.x >> 6;
    const int lr = lane & 15;
    const int quad = lane >> 4;
    const int wr = w >> 1, wc = w & 1;
    const int rbase = blockIdx.x * 128;
    const int cbase = blockIdx.y * 128;
    const int dma_r = lane >> 3;                   // row within 8-row group
    const int dma_cc = ((lane & 7) ^ dma_r) * 8;   // swizzled source chunk

    f4v acc[4][4] = {};
    for (int kt = 0; kt < DD / 64; kt++) {
        const int k0 = kt * 64;
        __syncthreads();   // all waves done reading previous tile
#pragma unroll
        for (int t = 0; t < 4; t++) {
            const int g = w * 4 + t;               // 8-row group 0..15
            async_cp16(W + (size_t)(cbase + g * 8 + dma_r) * DD + k0 + dma_cc,
                       &sB[g * 512]);
            if (!AF32)
                async_cp16(Ab + (size_t)(rbase + g * 8 + dma_r) * DD + k0 + dma_cc,
                           &sA[g * 512]);
        }
        if (AF32) {
#pragma unroll
            for (int t = 0; t < 4; t++) {
                const int g = w * 4 + t;
#pragma unroll
                for (int i = 0; i < 2; i++) {
                    const int li = lane + i * 64;
                    const int row = li >> 4;          // 0..7
                    const int fcol = (li & 15) * 4;   // 0..60
                    const float4 f = *(const float4*)&Af[
                        (size_t)(rbase + g * 8 + row) * DD + k0 + fcol];
                    B4 pk;
                    pk.v[0] = __float2bfloat16(f.x);
                    pk.v[1] = __float2bfloat16(f.y);
                    pk.v[2] = __float2bfloat16(f.z);
                    pk.v[3] = __float2bfloat16(f.w);
                    const int chunk = fcol >> 3;
                    *(B4*)&sA[g * 512 + row * 64 + ((chunk ^ row) & 7) * 8 +
                              (fcol & 7)] = pk;
                }
            }
        }
        __syncthreads();   // vmcnt(0)+lgkmcnt(0) drain -> tile staged
#pragma unroll
        for (int s = 0; s < 2; s++) {
            s8v a[4], b[4];
#pragma unroll
            for (int i = 0; i < 4; i++) {
                const int row = wr * 64 + i * 16 + lr;
                a[i] = *(const s8v*)&sA[row * 64 + (((s * 4 + quad) ^ (row & 7)) * 8)];
            }
#pragma unroll
            for (int j = 0; j < 4; j++) {
                const int row = wc * 64 + j * 16 + lr;
                b[j] = *(const s8v*)&sB[row * 64 + (((s * 4 + quad) ^ (row & 7)) * 8)];
            }
#pragma unroll
            for (int i = 0; i < 4; i++)
#pragma unroll
                for (int j = 0; j < 4; j++)
                    acc[i][j] = SWAP
                        ? __builtin_amdgcn_mfma_f32_16x16x32_bf16(b[j], a[i], acc[i][j], 0, 0, 0)
                        : __builtin_amdgcn_mfma_f32_16x16x32_bf16(a[i], b[j], acc[i][j], 0, 0, 0);
        }
    }
    __syncthreads();   // all waves finished reading sA/sB before sE overwrite

    if (FUSED == 0) {
        // SWAP=1: m = rbase+wr*64+i*16+lr ; n = cbase+wc*64+j*16+quad*4+r
#pragma unroll
        for (int j = 0; j < 4; j++) {
            const int n = cbase + wc * 64 + j * 16 + quad * 4;
            const f4v bv = *(const f4v*)&bias[n];
#pragma unroll
            for (int i = 0; i < 4; i++) {
                const int m = rbase + wr * 64 + i * 16 + lr;
                float4 o;
                o.x = (acc[i][j][0] + bv[0]) * gatef;
                o.y = (acc[i][j][1] + bv[1]) * gatef;
                o.z = (acc[i][j][2] + bv[2]) * gatef;
                o.w = (acc[i][j][3] + bv[3]) * gatef;
                *(float4*)&out_f[(size_t)m * DD + n] = o;
            }
        }
        return;
    }

    if (SWAP) {
        // Q/K proj: out[((b*H+h)*L + l)*HD + hd]. LDS rows = m, 136-el pitch.
#pragma unroll
        for (int j = 0; j < 4; j++) {
            const int n_loc = wc * 64 + j * 16 + quad * 4;
            const f4v bv = *(const f4v*)&bias[cbase + n_loc];
#pragma unroll
            for (int i = 0; i < 4; i++) {
                const int m_loc = wr * 64 + i * 16 + lr;
                B4 pk;
                pk.v[0] = __float2bfloat16(acc[i][j][0] + bv[0]);
                pk.v[1] = __float2bfloat16(acc[i][j][1] + bv[1]);
                pk.v[2] = __float2bfloat16(acc[i][j][2] + bv[2]);
                pk.v[3] = __float2bfloat16(acc[i][j][3] + bv[3]);
                *(B4*)&sE[m_loc * 136 + n_loc] = pk;   // 8B, bank-spread
            }
        }
        __syncthreads();
        const int tid = threadIdx.x;
        const int mr_ = tid >> 4;
        const int n0 = (tid & 15) * 8;
#pragma unroll
        for (int ro = 0; ro < 8; ro++) {
            const int m_loc = ro * 16 + mr_;
            const s8v vv = *(const s8v*)&sE[m_loc * 136 + n0];
            const int m = rbase + m_loc;
            const int n = cbase + n0;
            const int b_ = m >> 11, l = m & (LL - 1);
            const int h = n >> 6, hd = n & 63;
            *(s8v*)&out_bf[(((size_t)(b_ * HH + h)) * LL + l) * HD + hd] = vv;
        }
    } else {
        // V proj (transposed out[((b*H+h)*HD + hd)*L + l]). LDS rows = n.
#pragma unroll
        for (int j = 0; j < 4; j++) {
            const int n_loc = wc * 64 + j * 16 + lr;
            const float bv = bias[cbase + n_loc];
#pragma unroll
            for (int i = 0; i < 4; i++) {
                const int m0 = wr * 64 + i * 16 + quad * 4;
                B4 pk;
                pk.v[0] = __float2bfloat16(acc[i][j][0] + bv);
                pk.v[1] = __float2bfloat16(acc[i][j][1] + bv);
                pk.v[2] = __float2bfloat16(acc[i][j][2] + bv);
                pk.v[3] = __float2bfloat16(acc[i][j][3] + bv);
                *(B4*)&sE[n_loc * 136 + m0] = pk;      // 8B, bank-spread
            }
        }
        __syncthreads();
        const int tid = threadIdx.x;
#pragma unroll
        for (int ro = 0; ro < 8; ro++) {
            const int n_loc = ro * 16 + (tid >> 4);
            const int m0 = (tid & 15) * 8;
            const s8v vv = *(const s8v*)&sE[n_loc * 136 + m0];
            const int n = cbase + n_loc;
            const int m = rbase + m0;
            const int b_ = m >> 11, l = m & (LL - 1);
            const int h = n >> 6, hd = n & 63;
            *(s8v*)&out_bf[(((size_t)(b_ * HH + h)) * HD + hd) * LL + l] = vv;
        }
    }
}

template <int FUSED>
__global__ __launch_bounds__(256) void gemm128(QkvArgs qa,
                                               const bf16* __restrict__ Ao,
                                               const bf16* __restrict__ Wo_,
                                               const float* __restrict__ bo_,
                                               float* __restrict__ out_f,
                                               const int* __restrict__ mask) {
    __shared__ __align__(16) char smem[128 * 136 * 2];   // 34816 B
    __shared__ int sgate;

    float gatef = 1.0f;
    if (!FUSED) {
        if (threadIdx.x == 0) sgate = 0;
        __syncthreads();
        const int b_ = (int)(blockIdx.x * 128) >> 11;
        int any = 0;
        for (int i = threadIdx.x; i < LL; i += 256) any |= mask[b_ * LL + i];
        if (any) sgate = 1;   // benign same-value race
        __syncthreads();
        gatef = sgate ? 1.0f : 0.0f;
    }

    if (FUSED) {
        const int which = blockIdx.z;
        if (which != 2)
            gemm_body<1, 1, 1>(qa.A[which], qa.W[which], qa.bias[which],
                               qa.out[which], nullptr, 1.0f, smem);
        else
            gemm_body<1, 0, 1>(qa.A[2], qa.W[2], qa.bias[2],
                               qa.out[2], nullptr, 1.0f, smem);
    } else {
        gemm_body<0, 1, 0>(Ao, Wo_, bo_, nullptr, out_f, gatef, smem);
    }
}

// ---------------------------------------------------------------------------
// Flash attention, S^T form, log2-domain softmax WITHOUT max tracking.
// (unchanged from round 6: 72.5 us, bank-conflict 0, VALUBusy 57)
// Block = (b,h,128q), 8 waves x 16q sharing K/V LDS tiles (40 KB LDS, grid
// 512 = 2 blocks/CU), double-buffered DMA staging. Zero-exchange P via
// permuted K-row loads; per-lane denominator accumulated across tiles,
// reduced with 2 shuffles at the end. s_setprio(1) around MFMA clusters.
// ---------------------------------------------------------------------------
__global__ __launch_bounds__(512) void attn_kernel(const bf16* __restrict__ Q,
                                                   const bf16* __restrict__ K,
                                                   const bf16* __restrict__ Vt,
                                                   const int* __restrict__ mask,
                                                   bf16* __restrict__ Aout) {
    __shared__ bf16 sK[2][64 * 64];    // 16 KB
    __shared__ bf16 sV[2][64 * 64];    // 16 KB
    __shared__ float sBias[LL];        // 8 KB log2-domain additive bias

    const int lane = threadIdx.x & 63;
    const int w = threadIdx.x >> 6;    // 0..7
    const int lr = lane & 15;
    const int quad = lane >> 4;

    const int bid = blockIdx.x;
    const int qb = bid & 15;           // 16 q-blocks of 128
    const int h = (bid >> 4) & 15;
    const int b = bid >> 8;

    const size_t head_off = ((size_t)(b * HH + h)) * LL * HD;
    const bf16* Qh = Q + head_off;
    const bf16* Kh = K + head_off;
    const bf16* Vh = Vt + head_off;    // [HD][LL] per head
    const int q0 = qb * 128 + w * 16;

    const int dma_r = lane >> 3;
    // V staging: store chunk c of row r at position c ^ (r&7)
    const int dma_cv = ((lane & 7) ^ dma_r) * 8;
    // K staging: store chunk c of row r at position c ^ ((r&3)|(((r>>3)&1)<<2))
    // row = w*8 + dma_r -> r&3 = dma_r&3, (r>>3)&1 = w&1
    const int dma_ck = ((lane & 7) ^ ((dma_r & 3) | ((w & 1) << 2))) * 8;

    // prologue: bias fill + stage tile 0 (K and V); wave w stages group w
    {
        const int* mb = mask + b * LL;
        for (int i = threadIdx.x; i < LL; i += 512)
            sBias[i] = mb[i] ? 0.0f : MASK_B2;
        async_cp16(Kh + (size_t)(w * 8 + dma_r) * HD + dma_ck, &sK[0][w * 512]);
        async_cp16(Vh + (size_t)(w * 8 + dma_r) * LL + dma_cv, &sV[0][w * 512]);
    }
    __syncthreads();

    const s8v aq0 = *(const s8v*)(Qh + (size_t)(q0 + lr) * HD + quad * 8);
    const s8v aq1 = *(const s8v*)(Qh + (size_t)(q0 + lr) * HD + 32 + quad * 8);

    f4v O[4] = {};
    float lacc = 0.0f;   // per-lane denominator partial (reduced once at end)

    const int swk = (lr & 3) | (((lr >> 2) & 1) << 2);   // = sK(row(j,lr))
    const int swv = lr & 7;
    const int krow0 = 8 * (lr >> 2) + (lr & 3);

    for (int kt = 0; kt < LL / 64; kt++) {
        const int kbase = kt * 64;
        const bf16* kb = &sK[kt & 1][0];
        const bf16* vb = &sV[kt & 1][0];

        // stage next K+V tile into the other buffer (1 group per wave)
        if (kt < LL / 64 - 1) {
            const int nb = (kt + 1) & 1;
            async_cp16(Kh + (size_t)(kbase + 64 + w * 8 + dma_r) * HD + dma_ck,
                       &sK[nb][w * 512]);
            async_cp16(Vh + (size_t)(w * 8 + dma_r) * LL + kbase + 64 + dma_cv,
                       &sV[nb][w * 512]);
        }

        // T = K Q^T with permuted key rows: T[j][r] at (lr,quad) holds
        // S[key = 32*(j>>1) + 8*quad + 4*(j&1) + r][q = lr]
        f4v T[4];
        __builtin_amdgcn_s_setprio(1);
#pragma unroll
        for (int j = 0; j < 4; j++) {
            const int row = krow0 + 32 * (j >> 1) + 4 * (j & 1);
            const s8v kb0 = *(const s8v*)&kb[row * 64 + ((quad ^ swk) * 8)];
            const s8v kb1 = *(const s8v*)&kb[row * 64 + (((quad + 4) ^ swk) * 8)];
            f4v t = {};
            t = __builtin_amdgcn_mfma_f32_16x16x32_bf16(kb0, aq0, t, 0, 0, 0);
            T[j] = __builtin_amdgcn_mfma_f32_16x16x32_bf16(kb1, aq1, t, 0, 0, 0);
        }
        __builtin_amdgcn_s_setprio(0);

        // V fragments (A-operand of O^T): lane holds V^T[d=dt*16+lr][k]
        s8v v0[4], v1[4];
#pragma unroll
        for (int dt = 0; dt < 4; dt++) {
            const int vrow = dt * 16 + lr;
            v0[dt] = *(const s8v*)&vb[vrow * 64 + ((quad ^ swv) * 8)];
            v1[dt] = *(const s8v*)&vb[vrow * 64 + (((quad + 4) ^ swv) * 8)];
        }

        // P = exp2(S*CSCALE + bias) directly; accumulate per-lane denom
        union { s8v v; bf16 e[8]; } p0, p1;
#pragma unroll
        for (int j = 0; j < 4; j++) {
            const f4v bj = *(const f4v*)&sBias[kbase + 32 * (j >> 1) + 8 * quad + 4 * (j & 1)];
#pragma unroll
            for (int r = 0; r < 4; r++) {
                const float e = exp2f(T[j][r] * CSCALE + bj[r]);
                T[j][r] = e;
                lacc += e;
            }
        }
#pragma unroll
        for (int r = 0; r < 4; r++) {
            p0.e[r]     = __float2bfloat16(T[0][r]);
            p0.e[r + 4] = __float2bfloat16(T[1][r]);
            p1.e[r]     = __float2bfloat16(T[2][r]);
            p1.e[r + 4] = __float2bfloat16(T[3][r]);
        }

        // O^T[d][q] += V^T-frag * P-frag
        __builtin_amdgcn_s_setprio(1);
#pragma unroll
        for (int dt = 0; dt < 4; dt++) {
            O[dt] = __builtin_amdgcn_mfma_f32_16x16x32_bf16(v0[dt], p0.v, O[dt], 0, 0, 0);
            O[dt] = __builtin_amdgcn_mfma_f32_16x16x32_bf16(v1[dt], p1.v, O[dt], 0, 0, 0);
        }
        __builtin_amdgcn_s_setprio(0);

        __syncthreads();   // buffer handoff (drains next-tile DMA)
    }

    // reduce denominator once: lanes {lr, lr+16, lr+32, lr+48} cover all keys
    float lt = lacc;
    lt += __shfl_xor(lt, 16);
    lt += __shfl_xor(lt, 32);
    const float linv = (lt > 0.0f) ? (1.0f / lt) : 0.0f;

    // O^T lane holds q = lr, d = dt*16 + quad*4 + r -> direct 8B stores
#pragma unroll
    for (int dt = 0; dt < 4; dt++) {
        B4 o;
#pragma unroll
        for (int r = 0; r < 4; r++) o.v[r] = __float2bfloat16(O[dt][r] * linv);
        *(B4*)&Aout[((size_t)(b * LL + q0 + lr)) * DD + h * HD + dt * 16 + quad * 4] = o;
    }
}

// ---------------------------------------------------------------------------
extern "C" void kernel_launch(void* const* d_in, const int* in_sizes, int n_in,
                              void* d_out, int out_size, void* d_ws, size_t ws_size,
                              hipStream_t stream) {
    const float* query = (const float*)d_in[0];
    const float* key   = (const float*)d_in[1];
    const float* value = (const float*)d_in[2];
    const float* Wq = (const float*)d_in[3];
    const float* bq = (const float*)d_in[4];
    const float* Wk = (const float*)d_in[5];
    const float* bk = (const float*)d_in[6];
    const float* Wv = (const float*)d_in[7];
    const float* bv = (const float*)d_in[8];
    const float* Wo = (const float*)d_in[9];
    const float* bo = (const float*)d_in[10];
    const int* mask = (const int*)d_in[11];

    bf16* base = (bf16*)d_ws;
    bf16* wq = base;
    bf16* wk = wq + DD * DD;
    bf16* wv = wk + DD * DD;
    bf16* wo = wv + DD * DD;
    bf16* Qs = wo + DD * DD;
    bf16* Ks = Qs + PER_T;
    bf16* Vst = Ks + PER_T;
    bf16* aws = Vst + PER_T;

    CvtArgs ca;
    ca.src[0] = Wq; ca.dst[0] = wq; ca.n[0] = DD * DD;
    ca.src[1] = Wk; ca.dst[1] = wk; ca.n[1] = DD * DD;
    ca.src[2] = Wv; ca.dst[2] = wv; ca.n[2] = DD * DD;
    ca.src[3] = Wo; ca.dst[3] = wo; ca.n[3] = DD * DD;
    cvt_kernel<<<dim3(256, 4), 256, 0, stream>>>(ca);

    QkvArgs qa;
    qa.A[0] = query; qa.W[0] = wq; qa.bias[0] = bq; qa.out[0] = Qs;
    qa.A[1] = key;   qa.W[1] = wk; qa.bias[1] = bk; qa.out[1] = Ks;
    qa.A[2] = value; qa.W[2] = wv; qa.bias[2] = bv; qa.out[2] = Vst;

    // fused Q/K/V projections (f32 A in-flight converted): 32x8x3 blocks
    gemm128<1><<<dim3(MTOT / 128, DD / 128, 3), 256, 0, stream>>>(
        qa, nullptr, nullptr, nullptr, nullptr, nullptr);

    // 8-wave blocks of 128 q (16 q per wave): 2*16*16 = 512 blocks, 2/CU
    attn_kernel<<<BB * HH * (LL / 128), 512, 0, stream>>>(Qs, Ks, Vst, mask, aws);

    QkvArgs dummy{};
    gemm128<0><<<dim3(MTOT / 128, DD / 128, 1), 256, 0, stream>>>(
        dummy, aws, wo, bo, (float*)d_out, mask);
}

// Round 8
// 245.997 us; speedup vs baseline: 1.0351x; 1.0351x over previous
//
#include <hip/hip_runtime.h>
#include <hip/hip_bf16.h>

typedef __hip_bfloat16 bf16;
typedef __attribute__((ext_vector_type(8))) short s8v;   // 8 x bf16 (4 VGPRs)
typedef __attribute__((ext_vector_type(4))) float f4v;   // MFMA accumulator

#define LOG2E 1.44269504088896340736f
#define CSCALE (0.125f * LOG2E)          // fold 1/sqrt(64) and log2e
#define MASK_B2 (-14426.950408889634f)   // -10000 * LOG2E (log2-domain bias)

#define BB 2
#define LL 2048
#define DD 1024
#define HH 16
#define HD 64
#define MTOT 4096
#define PER_T 4194304  // B*H*L*HD elements (8 MiB bf16)

struct alignas(8) B4 { bf16 v[4]; };

// async global->LDS 16B: data lands at lds_base + lane*16 (base wave-uniform)
__device__ __forceinline__ void async_cp16(const bf16* g, bf16* l) {
    __builtin_amdgcn_global_load_lds(
        (const __attribute__((address_space(1))) void*)g,
        (__attribute__((address_space(3))) void*)l, 16, 0, 0);
}

// ---------------------------------------------------------------------------
// f32 -> bf16 bulk conversion (3 activations + 4 weights)
// ---------------------------------------------------------------------------
struct CvtArgs {
    const float* src[7];
    bf16* dst[7];
    int n[7];
};

__global__ __launch_bounds__(256) void cvt_kernel(CvtArgs args) {
    const int which = blockIdx.y;
    const float* __restrict__ src = args.src[which];
    bf16* __restrict__ dst = args.dst[which];
    const int n4 = args.n[which] >> 2;
    const int stride = gridDim.x * 256;
    for (int i = blockIdx.x * 256 + threadIdx.x; i < n4; i += stride) {
        const float4 f = ((const float4*)src)[i];
        B4 o;
        o.v[0] = __float2bfloat16(f.x);
        o.v[1] = __float2bfloat16(f.y);
        o.v[2] = __float2bfloat16(f.z);
        o.v[3] = __float2bfloat16(f.w);
        ((B4*)dst)[i] = o;
    }
}

// ---------------------------------------------------------------------------
// m97-style GEMM: C[m,n] = A[m,:].W[n,:] + bias[n]; 128x128 tile, BK=64,
// single-buffered LDS (2-barrier K-loop), global_load_lds w16, XOR swizzle.
// 4 waves in 2x2, each 64x64 (acc[4][4]); 16 MFMA : 8 ds_read_b128 per k-step.
//   SWAP=1 (Q/K proj, O proj): mfma(b,a) -> lane holds 4 consecutive n.
//     O proj: direct float4 stores (no LDS). Q/K: bf16 via LDS [m][136].
//   SWAP=0 (V proj, transposed output): mfma(a,b) -> 4 consecutive m;
//     LDS [n][136], read back 8 consecutive l -> 16B stores along l.
// ---------------------------------------------------------------------------
struct QkvArgs {
    const bf16* A[3];
    const bf16* W[3];
    const float* bias[3];
    bf16* out[3];
};

template <int FUSED, int SWAP>
__device__ __forceinline__ void gemm_body(const bf16* __restrict__ A,
                                          const bf16* __restrict__ W,
                                          const float* __restrict__ bias,
                                          bf16* __restrict__ out_bf,
                                          float* __restrict__ out_f,
                                          float gatef, char* smem) {
    bf16* sA = (bf16*)smem;                    // 16 KB
    bf16* sB = (bf16*)(smem + 128 * 64 * 2);   // 16 KB
    bf16* sE = (bf16*)smem;                    // epilogue transpose, 34 KB

    const int lane = threadIdx.x & 63;
    const int w = threadIdx.x >> 6;
    const int lr = lane & 15;
    const int quad = lane >> 4;
    const int wr = w >> 1, wc = w & 1;
    const int rbase = blockIdx.x * 128;
    const int cbase = blockIdx.y * 128;
    const int dma_r = lane >> 3;                   // row within 8-row group
    const int dma_cc = ((lane & 7) ^ dma_r) * 8;   // swizzled source chunk

    f4v acc[4][4] = {};
    for (int kt = 0; kt < DD / 64; kt++) {
        const int k0 = kt * 64;
        __syncthreads();   // all waves done reading previous tile
#pragma unroll
        for (int t = 0; t < 4; t++) {
            const int g = w * 4 + t;               // 8-row group 0..15
            async_cp16(A + (size_t)(rbase + g * 8 + dma_r) * DD + k0 + dma_cc,
                       &sA[g * 512]);
            async_cp16(W + (size_t)(cbase + g * 8 + dma_r) * DD + k0 + dma_cc,
                       &sB[g * 512]);
        }
        __syncthreads();   // implicit vmcnt(0) drain -> tile staged
#pragma unroll
        for (int s = 0; s < 2; s++) {
            s8v a[4], b[4];
#pragma unroll
            for (int i = 0; i < 4; i++) {
                const int row = wr * 64 + i * 16 + lr;
                a[i] = *(const s8v*)&sA[row * 64 + (((s * 4 + quad) ^ (row & 7)) * 8)];
            }
#pragma unroll
            for (int j = 0; j < 4; j++) {
                const int row = wc * 64 + j * 16 + lr;
                b[j] = *(const s8v*)&sB[row * 64 + (((s * 4 + quad) ^ (row & 7)) * 8)];
            }
#pragma unroll
            for (int i = 0; i < 4; i++)
#pragma unroll
                for (int j = 0; j < 4; j++)
                    acc[i][j] = SWAP
                        ? __builtin_amdgcn_mfma_f32_16x16x32_bf16(b[j], a[i], acc[i][j], 0, 0, 0)
                        : __builtin_amdgcn_mfma_f32_16x16x32_bf16(a[i], b[j], acc[i][j], 0, 0, 0);
        }
    }
    __syncthreads();   // all waves finished reading sA/sB before sE overwrite

    if (FUSED == 0) {
        // SWAP=1: m = rbase+wr*64+i*16+lr ; n = cbase+wc*64+j*16+quad*4+r
#pragma unroll
        for (int j = 0; j < 4; j++) {
            const int n = cbase + wc * 64 + j * 16 + quad * 4;
            const f4v bv = *(const f4v*)&bias[n];
#pragma unroll
            for (int i = 0; i < 4; i++) {
                const int m = rbase + wr * 64 + i * 16 + lr;
                float4 o;
                o.x = (acc[i][j][0] + bv[0]) * gatef;
                o.y = (acc[i][j][1] + bv[1]) * gatef;
                o.z = (acc[i][j][2] + bv[2]) * gatef;
                o.w = (acc[i][j][3] + bv[3]) * gatef;
                *(float4*)&out_f[(size_t)m * DD + n] = o;
            }
        }
        return;
    }

    if (SWAP) {
        // Q/K proj: out[((b*H+h)*L + l)*HD + hd]. LDS rows = m, 136-el pitch.
#pragma unroll
        for (int j = 0; j < 4; j++) {
            const int n_loc = wc * 64 + j * 16 + quad * 4;
            const f4v bv = *(const f4v*)&bias[cbase + n_loc];
#pragma unroll
            for (int i = 0; i < 4; i++) {
                const int m_loc = wr * 64 + i * 16 + lr;
                B4 pk;
                pk.v[0] = __float2bfloat16(acc[i][j][0] + bv[0]);
                pk.v[1] = __float2bfloat16(acc[i][j][1] + bv[1]);
                pk.v[2] = __float2bfloat16(acc[i][j][2] + bv[2]);
                pk.v[3] = __float2bfloat16(acc[i][j][3] + bv[3]);
                *(B4*)&sE[m_loc * 136 + n_loc] = pk;   // 8B, bank-spread
            }
        }
        __syncthreads();
        const int tid = threadIdx.x;
        const int mr_ = tid >> 4;
        const int n0 = (tid & 15) * 8;
#pragma unroll
        for (int ro = 0; ro < 8; ro++) {
            const int m_loc = ro * 16 + mr_;
            const s8v vv = *(const s8v*)&sE[m_loc * 136 + n0];
            const int m = rbase + m_loc;
            const int n = cbase + n0;
            const int b_ = m >> 11, l = m & (LL - 1);
            const int h = n >> 6, hd = n & 63;
            *(s8v*)&out_bf[(((size_t)(b_ * HH + h)) * LL + l) * HD + hd] = vv;
        }
    } else {
        // V proj (transposed out[((b*H+h)*HD + hd)*L + l]). LDS rows = n.
#pragma unroll
        for (int j = 0; j < 4; j++) {
            const int n_loc = wc * 64 + j * 16 + lr;
            const float bv = bias[cbase + n_loc];
#pragma unroll
            for (int i = 0; i < 4; i++) {
                const int m0 = wr * 64 + i * 16 + quad * 4;
                B4 pk;
                pk.v[0] = __float2bfloat16(acc[i][j][0] + bv);
                pk.v[1] = __float2bfloat16(acc[i][j][1] + bv);
                pk.v[2] = __float2bfloat16(acc[i][j][2] + bv);
                pk.v[3] = __float2bfloat16(acc[i][j][3] + bv);
                *(B4*)&sE[n_loc * 136 + m0] = pk;      // 8B, bank-spread
            }
        }
        __syncthreads();
        const int tid = threadIdx.x;
#pragma unroll
        for (int ro = 0; ro < 8; ro++) {
            const int n_loc = ro * 16 + (tid >> 4);
            const int m0 = (tid & 15) * 8;
            const s8v vv = *(const s8v*)&sE[n_loc * 136 + m0];
            const int n = cbase + n_loc;
            const int m = rbase + m0;
            const int b_ = m >> 11, l = m & (LL - 1);
            const int h = n >> 6, hd = n & 63;
            *(s8v*)&out_bf[(((size_t)(b_ * HH + h)) * HD + hd) * LL + l] = vv;
        }
    }
}

template <int FUSED>
__global__ __launch_bounds__(256) void gemm128(QkvArgs qa,
                                               const bf16* __restrict__ Ao,
                                               const bf16* __restrict__ Wo_,
                                               const float* __restrict__ bo_,
                                               float* __restrict__ out_f,
                                               const int* __restrict__ mask) {
    __shared__ __align__(16) char smem[128 * 136 * 2];   // 34816 B
    __shared__ int sgate;

    float gatef = 1.0f;
    if (!FUSED) {
        if (threadIdx.x == 0) sgate = 0;
        __syncthreads();
        const int b_ = (int)(blockIdx.x * 128) >> 11;
        int any = 0;
        for (int i = threadIdx.x; i < LL; i += 256) any |= mask[b_ * LL + i];
        if (any) sgate = 1;   // benign same-value race
        __syncthreads();
        gatef = sgate ? 1.0f : 0.0f;
    }

    if (FUSED) {
        const int which = blockIdx.z;
        if (which != 2)
            gemm_body<1, 1>(qa.A[which], qa.W[which], qa.bias[which],
                            qa.out[which], nullptr, 1.0f, smem);
        else
            gemm_body<1, 0>(qa.A[2], qa.W[2], qa.bias[2],
                            qa.out[2], nullptr, 1.0f, smem);
    } else {
        gemm_body<0, 1>(Ao, Wo_, bo_, nullptr, out_f, gatef, smem);
    }
}

// ---------------------------------------------------------------------------
// Flash attention, S^T form, log2-domain softmax WITHOUT max tracking
// (round 6 structure: 72.5 us, bank-conflict 0). This round: softmax VALU
// expressed as f4v vector arithmetic (pk_fma/pk_add candidates) and packed
// bf16 conversions via __float22bfloat162_rn (HW v_cvt_pk_bf16_f32, same RNE
// rounding -> bit-identical results). Denominator accumulated as per-lane
// f4v across tiles, reduced once at the end.
//
// Block = (b,h,128q), 8 waves x 16q sharing K/V LDS tiles (40 KB LDS, grid
// 512 = 2 blocks/CU), double-buffered DMA staging. Zero-exchange P via
// permuted K-row loads; s_setprio(1) around MFMA clusters.
// ---------------------------------------------------------------------------
__global__ __launch_bounds__(512) void attn_kernel(const bf16* __restrict__ Q,
                                                   const bf16* __restrict__ K,
                                                   const bf16* __restrict__ Vt,
                                                   const int* __restrict__ mask,
                                                   bf16* __restrict__ Aout) {
    __shared__ bf16 sK[2][64 * 64];    // 16 KB
    __shared__ bf16 sV[2][64 * 64];    // 16 KB
    __shared__ float sBias[LL];        // 8 KB log2-domain additive bias

    const int lane = threadIdx.x & 63;
    const int w = threadIdx.x >> 6;    // 0..7
    const int lr = lane & 15;
    const int quad = lane >> 4;

    const int bid = blockIdx.x;
    const int qb = bid & 15;           // 16 q-blocks of 128
    const int h = (bid >> 4) & 15;
    const int b = bid >> 8;

    const size_t head_off = ((size_t)(b * HH + h)) * LL * HD;
    const bf16* Qh = Q + head_off;
    const bf16* Kh = K + head_off;
    const bf16* Vh = Vt + head_off;    // [HD][LL] per head
    const int q0 = qb * 128 + w * 16;

    const int dma_r = lane >> 3;
    // V staging: store chunk c of row r at position c ^ (r&7)
    const int dma_cv = ((lane & 7) ^ dma_r) * 8;
    // K staging: store chunk c of row r at position c ^ ((r&3)|(((r>>3)&1)<<2))
    // row = w*8 + dma_r -> r&3 = dma_r&3, (r>>3)&1 = w&1
    const int dma_ck = ((lane & 7) ^ ((dma_r & 3) | ((w & 1) << 2))) * 8;

    // prologue: bias fill + stage tile 0 (K and V); wave w stages group w
    {
        const int* mb = mask + b * LL;
        for (int i = threadIdx.x; i < LL; i += 512)
            sBias[i] = mb[i] ? 0.0f : MASK_B2;
        async_cp16(Kh + (size_t)(w * 8 + dma_r) * HD + dma_ck, &sK[0][w * 512]);
        async_cp16(Vh + (size_t)(w * 8 + dma_r) * LL + dma_cv, &sV[0][w * 512]);
    }
    __syncthreads();

    const s8v aq0 = *(const s8v*)(Qh + (size_t)(q0 + lr) * HD + quad * 8);
    const s8v aq1 = *(const s8v*)(Qh + (size_t)(q0 + lr) * HD + 32 + quad * 8);

    f4v O[4] = {};
    f4v lacc4 = {};   // per-lane denominator partials (reduced once at end)

    const int swk = (lr & 3) | (((lr >> 2) & 1) << 2);   // = sK(row(j,lr))
    const int swv = lr & 7;
    const int krow0 = 8 * (lr >> 2) + (lr & 3);

    for (int kt = 0; kt < LL / 64; kt++) {
        const int kbase = kt * 64;
        const bf16* kb = &sK[kt & 1][0];
        const bf16* vb = &sV[kt & 1][0];

        // stage next K+V tile into the other buffer (1 group per wave)
        if (kt < LL / 64 - 1) {
            const int nb = (kt + 1) & 1;
            async_cp16(Kh + (size_t)(kbase + 64 + w * 8 + dma_r) * HD + dma_ck,
                       &sK[nb][w * 512]);
            async_cp16(Vh + (size_t)(w * 8 + dma_r) * LL + kbase + 64 + dma_cv,
                       &sV[nb][w * 512]);
        }

        // T = K Q^T with permuted key rows: T[j][r] at (lr,quad) holds
        // S[key = 32*(j>>1) + 8*quad + 4*(j&1) + r][q = lr]
        f4v T[4];
        __builtin_amdgcn_s_setprio(1);
#pragma unroll
        for (int j = 0; j < 4; j++) {
            const int row = krow0 + 32 * (j >> 1) + 4 * (j & 1);
            const s8v kb0 = *(const s8v*)&kb[row * 64 + ((quad ^ swk) * 8)];
            const s8v kb1 = *(const s8v*)&kb[row * 64 + (((quad + 4) ^ swk) * 8)];
            f4v t = {};
            t = __builtin_amdgcn_mfma_f32_16x16x32_bf16(kb0, aq0, t, 0, 0, 0);
            T[j] = __builtin_amdgcn_mfma_f32_16x16x32_bf16(kb1, aq1, t, 0, 0, 0);
        }
        __builtin_amdgcn_s_setprio(0);

        // V fragments (A-operand of O^T): lane holds V^T[d=dt*16+lr][k]
        s8v v0[4], v1[4];
#pragma unroll
        for (int dt = 0; dt < 4; dt++) {
            const int vrow = dt * 16 + lr;
            v0[dt] = *(const s8v*)&vb[vrow * 64 + ((quad ^ swv) * 8)];
            v1[dt] = *(const s8v*)&vb[vrow * 64 + (((quad + 4) ^ swv) * 8)];
        }

        // P = exp2(S*CSCALE + bias), vector form; accumulate per-lane denom
#pragma unroll
        for (int j = 0; j < 4; j++) {
            const f4v bj = *(const f4v*)&sBias[kbase + 32 * (j >> 1) + 8 * quad + 4 * (j & 1)];
            T[j] = T[j] * CSCALE + bj;       // f4v fma (pk candidates)
#pragma unroll
            for (int r = 0; r < 4; r++) T[j][r] = exp2f(T[j][r]);
            lacc4 += T[j];                   // f4v add
        }

        // pack P into PV B-operand fragments via packed HW cvt (RNE,
        // bit-identical to __float2bfloat16)
        union { s8v v; __hip_bfloat162 h[4]; } p0, p1;
        p0.h[0] = __float22bfloat162_rn(make_float2(T[0][0], T[0][1]));
        p0.h[1] = __float22bfloat162_rn(make_float2(T[0][2], T[0][3]));
        p0.h[2] = __float22bfloat162_rn(make_float2(T[1][0], T[1][1]));
        p0.h[3] = __float22bfloat162_rn(make_float2(T[1][2], T[1][3]));
        p1.h[0] = __float22bfloat162_rn(make_float2(T[2][0], T[2][1]));
        p1.h[1] = __float22bfloat162_rn(make_float2(T[2][2], T[2][3]));
        p1.h[2] = __float22bfloat162_rn(make_float2(T[3][0], T[3][1]));
        p1.h[3] = __float22bfloat162_rn(make_float2(T[3][2], T[3][3]));

        // O^T[d][q] += V^T-frag * P-frag
        __builtin_amdgcn_s_setprio(1);
#pragma unroll
        for (int dt = 0; dt < 4; dt++) {
            O[dt] = __builtin_amdgcn_mfma_f32_16x16x32_bf16(v0[dt], p0.v, O[dt], 0, 0, 0);
            O[dt] = __builtin_amdgcn_mfma_f32_16x16x32_bf16(v1[dt], p1.v, O[dt], 0, 0, 0);
        }
        __builtin_amdgcn_s_setprio(0);

        __syncthreads();   // buffer handoff (drains next-tile DMA)
    }

    // reduce denominator once: lanes {lr, lr+16, lr+32, lr+48} cover all keys
    float lt = (lacc4[0] + lacc4[1]) + (lacc4[2] + lacc4[3]);
    lt += __shfl_xor(lt, 16);
    lt += __shfl_xor(lt, 32);
    const float linv = (lt > 0.0f) ? (1.0f / lt) : 0.0f;

    // O^T lane holds q = lr, d = dt*16 + quad*4 + r -> direct 8B stores
#pragma unroll
    for (int dt = 0; dt < 4; dt++) {
        union { B4 b4; __hip_bfloat162 h[2]; } o;
        o.h[0] = __float22bfloat162_rn(make_float2(O[dt][0] * linv, O[dt][1] * linv));
        o.h[1] = __float22bfloat162_rn(make_float2(O[dt][2] * linv, O[dt][3] * linv));
        *(B4*)&Aout[((size_t)(b * LL + q0 + lr)) * DD + h * HD + dt * 16 + quad * 4] = o.b4;
    }
}

// ---------------------------------------------------------------------------
extern "C" void kernel_launch(void* const* d_in, const int* in_sizes, int n_in,
                              void* d_out, int out_size, void* d_ws, size_t ws_size,
                              hipStream_t stream) {
    const float* query = (const float*)d_in[0];
    const float* key   = (const float*)d_in[1];
    const float* value = (const float*)d_in[2];
    const float* Wq = (const float*)d_in[3];
    const float* bq = (const float*)d_in[4];
    const float* Wk = (const float*)d_in[5];
    const float* bk = (const float*)d_in[6];
    const float* Wv = (const float*)d_in[7];
    const float* bv = (const float*)d_in[8];
    const float* Wo = (const float*)d_in[9];
    const float* bo = (const float*)d_in[10];
    const int* mask = (const int*)d_in[11];

    bf16* base = (bf16*)d_ws;
    bf16* qx = base;
    bf16* kx = qx + PER_T;
    bf16* vx = kx + PER_T;
    bf16* wq = vx + PER_T;
    bf16* wk = wq + DD * DD;
    bf16* wv = wk + DD * DD;
    bf16* wo = wv + DD * DD;
    bf16* Qs = wo + DD * DD;
    bf16* Ks = Qs + PER_T;
    bf16* Vst = Ks + PER_T;
    bf16* aws = Vst + PER_T;

    CvtArgs ca;
    ca.src[0] = query; ca.dst[0] = qx; ca.n[0] = PER_T;
    ca.src[1] = key;   ca.dst[1] = kx; ca.n[1] = PER_T;
    ca.src[2] = value; ca.dst[2] = vx; ca.n[2] = PER_T;
    ca.src[3] = Wq;    ca.dst[3] = wq; ca.n[3] = DD * DD;
    ca.src[4] = Wk;    ca.dst[4] = wk; ca.n[4] = DD * DD;
    ca.src[5] = Wv;    ca.dst[5] = wv; ca.n[5] = DD * DD;
    ca.src[6] = Wo;    ca.dst[6] = wo; ca.n[6] = DD * DD;
    cvt_kernel<<<dim3(1024, 7), 256, 0, stream>>>(ca);

    QkvArgs qa;
    qa.A[0] = qx; qa.W[0] = wq; qa.bias[0] = bq; qa.out[0] = Qs;
    qa.A[1] = kx; qa.W[1] = wk; qa.bias[1] = bk; qa.out[1] = Ks;
    qa.A[2] = vx; qa.W[2] = wv; qa.bias[2] = bv; qa.out[2] = Vst;

    // fused Q/K/V projections: 32 x 8 x 3 = 768 blocks (~3/CU)
    gemm128<1><<<dim3(MTOT / 128, DD / 128, 3), 256, 0, stream>>>(
        qa, nullptr, nullptr, nullptr, nullptr, nullptr);

    // 8-wave blocks of 128 q (16 q per wave): 2*16*16 = 512 blocks, 2/CU
    attn_kernel<<<BB * HH * (LL / 128), 512, 0, stream>>>(Qs, Ks, Vst, mask, aws);

    QkvArgs dummy{};
    gemm128<0><<<dim3(MTOT / 128, DD / 128, 1), 256, 0, stream>>>(
        dummy, aws, wo, bo, (float*)d_out, mask);
}

// Round 9
// 237.963 us; speedup vs baseline: 1.0701x; 1.0338x over previous
//
#include <hip/hip_runtime.h>
#include <hip/hip_bf16.h>

typedef __hip_bfloat16 bf16;
typedef __attribute__((ext_vector_type(8))) short s8v;   // 8 x bf16 (4 VGPRs)
typedef __attribute__((ext_vector_type(4))) float f4v;   // MFMA accumulator

#define LOG2E 1.44269504088896340736f
#define CSCALE (0.125f * LOG2E)          // fold 1/sqrt(64) and log2e
#define MASK_B2 (-14426.950408889634f)   // -10000 * LOG2E (log2-domain bias)

#define BB 2
#define LL 2048
#define DD 1024
#define HH 16
#define HD 64
#define MTOT 4096
#define PER_T 4194304  // B*H*L*HD elements (8 MiB bf16)

struct alignas(8) B4 { bf16 v[4]; };

// async global->LDS 16B: data lands at lds_base + lane*16 (base wave-uniform)
__device__ __forceinline__ void async_cp16(const bf16* g, bf16* l) {
    __builtin_amdgcn_global_load_lds(
        (const __attribute__((address_space(1))) void*)g,
        (__attribute__((address_space(3))) void*)l, 16, 0, 0);
}

// ---------------------------------------------------------------------------
// f32 -> bf16 bulk conversion (3 activations + 4 weights)
// ---------------------------------------------------------------------------
struct CvtArgs {
    const float* src[7];
    bf16* dst[7];
    int n[7];
};

__global__ __launch_bounds__(256) void cvt_kernel(CvtArgs args) {
    const int which = blockIdx.y;
    const float* __restrict__ src = args.src[which];
    bf16* __restrict__ dst = args.dst[which];
    const int n4 = args.n[which] >> 2;
    const int stride = gridDim.x * 256;
    for (int i = blockIdx.x * 256 + threadIdx.x; i < n4; i += stride) {
        const float4 f = ((const float4*)src)[i];
        B4 o;
        o.v[0] = __float2bfloat16(f.x);
        o.v[1] = __float2bfloat16(f.y);
        o.v[2] = __float2bfloat16(f.z);
        o.v[3] = __float2bfloat16(f.w);
        ((B4*)dst)[i] = o;
    }
}

// ---------------------------------------------------------------------------
// QKV GEMM (m97-style): C[m,n] = A[m,:].W[n,:] + bias[n]; 128x128 tile,
// BK=64, single-buffered LDS (2-barrier K-loop), global_load_lds w16, XOR
// swizzle. 4 waves 2x2, each 64x64 (acc[4][4]).
//   SWAP=1 (Q/K proj): mfma(b,a) -> lane holds 4 consecutive n; bf16 out via
//     LDS [m][136] transpose -> coalesced 16B stores.
//   SWAP=0 (V proj, transposed output): mfma(a,b) -> 4 consecutive m;
//     LDS [n][136], read back 8 consecutive l -> 16B stores along l.
// ---------------------------------------------------------------------------
struct QkvArgs {
    const bf16* A[3];
    const bf16* W[3];
    const float* bias[3];
    bf16* out[3];
};

template <int SWAP>
__device__ __forceinline__ void gemm_body(const bf16* __restrict__ A,
                                          const bf16* __restrict__ W,
                                          const float* __restrict__ bias,
                                          bf16* __restrict__ out_bf,
                                          char* smem) {
    bf16* sA = (bf16*)smem;                    // 16 KB
    bf16* sB = (bf16*)(smem + 128 * 64 * 2);   // 16 KB
    bf16* sE = (bf16*)smem;                    // epilogue transpose, 34 KB

    const int lane = threadIdx.x & 63;
    const int w = threadIdx.x >> 6;
    const int lr = lane & 15;
    const int quad = lane >> 4;
    const int wr = w >> 1, wc = w & 1;
    const int rbase = blockIdx.x * 128;
    const int cbase = blockIdx.y * 128;
    const int dma_r = lane >> 3;                   // row within 8-row group
    const int dma_cc = ((lane & 7) ^ dma_r) * 8;   // swizzled source chunk

    f4v acc[4][4] = {};
    for (int kt = 0; kt < DD / 64; kt++) {
        const int k0 = kt * 64;
        __syncthreads();   // all waves done reading previous tile
#pragma unroll
        for (int t = 0; t < 4; t++) {
            const int g = w * 4 + t;               // 8-row group 0..15
            async_cp16(A + (size_t)(rbase + g * 8 + dma_r) * DD + k0 + dma_cc,
                       &sA[g * 512]);
            async_cp16(W + (size_t)(cbase + g * 8 + dma_r) * DD + k0 + dma_cc,
                       &sB[g * 512]);
        }
        __syncthreads();   // implicit vmcnt(0) drain -> tile staged
#pragma unroll
        for (int s = 0; s < 2; s++) {
            s8v a[4], b[4];
#pragma unroll
            for (int i = 0; i < 4; i++) {
                const int row = wr * 64 + i * 16 + lr;
                a[i] = *(const s8v*)&sA[row * 64 + (((s * 4 + quad) ^ (row & 7)) * 8)];
            }
#pragma unroll
            for (int j = 0; j < 4; j++) {
                const int row = wc * 64 + j * 16 + lr;
                b[j] = *(const s8v*)&sB[row * 64 + (((s * 4 + quad) ^ (row & 7)) * 8)];
            }
#pragma unroll
            for (int i = 0; i < 4; i++)
#pragma unroll
                for (int j = 0; j < 4; j++)
                    acc[i][j] = SWAP
                        ? __builtin_amdgcn_mfma_f32_16x16x32_bf16(b[j], a[i], acc[i][j], 0, 0, 0)
                        : __builtin_amdgcn_mfma_f32_16x16x32_bf16(a[i], b[j], acc[i][j], 0, 0, 0);
        }
    }
    __syncthreads();   // all waves finished reading sA/sB before sE overwrite

    if (SWAP) {
        // Q/K proj: out[((b*H+h)*L + l)*HD + hd]. LDS rows = m, 136-el pitch.
#pragma unroll
        for (int j = 0; j < 4; j++) {
            const int n_loc = wc * 64 + j * 16 + quad * 4;
            const f4v bv = *(const f4v*)&bias[cbase + n_loc];
#pragma unroll
            for (int i = 0; i < 4; i++) {
                const int m_loc = wr * 64 + i * 16 + lr;
                B4 pk;
                pk.v[0] = __float2bfloat16(acc[i][j][0] + bv[0]);
                pk.v[1] = __float2bfloat16(acc[i][j][1] + bv[1]);
                pk.v[2] = __float2bfloat16(acc[i][j][2] + bv[2]);
                pk.v[3] = __float2bfloat16(acc[i][j][3] + bv[3]);
                *(B4*)&sE[m_loc * 136 + n_loc] = pk;   // 8B, bank-spread
            }
        }
        __syncthreads();
        const int tid = threadIdx.x;
        const int mr_ = tid >> 4;
        const int n0 = (tid & 15) * 8;
#pragma unroll
        for (int ro = 0; ro < 8; ro++) {
            const int m_loc = ro * 16 + mr_;
            const s8v vv = *(const s8v*)&sE[m_loc * 136 + n0];
            const int m = rbase + m_loc;
            const int n = cbase + n0;
            const int b_ = m >> 11, l = m & (LL - 1);
            const int h = n >> 6, hd = n & 63;
            *(s8v*)&out_bf[(((size_t)(b_ * HH + h)) * LL + l) * HD + hd] = vv;
        }
    } else {
        // V proj (transposed out[((b*H+h)*HD + hd)*L + l]). LDS rows = n.
#pragma unroll
        for (int j = 0; j < 4; j++) {
            const int n_loc = wc * 64 + j * 16 + lr;
            const float bv = bias[cbase + n_loc];
#pragma unroll
            for (int i = 0; i < 4; i++) {
                const int m0 = wr * 64 + i * 16 + quad * 4;
                B4 pk;
                pk.v[0] = __float2bfloat16(acc[i][j][0] + bv);
                pk.v[1] = __float2bfloat16(acc[i][j][1] + bv);
                pk.v[2] = __float2bfloat16(acc[i][j][2] + bv);
                pk.v[3] = __float2bfloat16(acc[i][j][3] + bv);
                *(B4*)&sE[n_loc * 136 + m0] = pk;      // 8B, bank-spread
            }
        }
        __syncthreads();
        const int tid = threadIdx.x;
#pragma unroll
        for (int ro = 0; ro < 8; ro++) {
            const int n_loc = ro * 16 + (tid >> 4);
            const int m0 = (tid & 15) * 8;
            const s8v vv = *(const s8v*)&sE[n_loc * 136 + m0];
            const int n = cbase + n_loc;
            const int m = rbase + m0;
            const int b_ = m >> 11, l = m & (LL - 1);
            const int h = n >> 6, hd = n & 63;
            *(s8v*)&out_bf[(((size_t)(b_ * HH + h)) * HD + hd) * LL + l] = vv;
        }
    }
}

__global__ __launch_bounds__(256) void gemm128(QkvArgs qa) {
    __shared__ __align__(16) char smem[128 * 136 * 2];   // 34816 B
    const int which = blockIdx.z;
    if (which != 2)
        gemm_body<1>(qa.A[which], qa.W[which], qa.bias[which], qa.out[which], smem);
    else
        gemm_body<0>(qa.A[2], qa.W[2], qa.bias[2], qa.out[2], smem);
}

// ---------------------------------------------------------------------------
// O-projection, 64x128 tile (this round): grid 64x8 = 512 blocks = 2/CU ->
// 8 waves/CU (old 128x128 grid was 256 blocks = 1 block/CU = 4 waves/CU,
// latency-starved). 4 waves 2x2, each 32x64 (acc[2][4]). No LDS epilogue:
// SWAP operand order gives lane 4 consecutive n -> direct coalesced float4
// stores. 24 KB LDS. Same staging/swizzle/MFMA pattern as gemm128.
// ---------------------------------------------------------------------------
__global__ __launch_bounds__(256) void oproj64(const bf16* __restrict__ A,
                                               const bf16* __restrict__ W,
                                               const float* __restrict__ bias,
                                               float* __restrict__ out_f,
                                               const int* __restrict__ mask) {
    __shared__ bf16 sA[64 * 64];     // 8 KB
    __shared__ bf16 sB[128 * 64];    // 16 KB
    __shared__ int sgate;

    const int lane = threadIdx.x & 63;
    const int w = threadIdx.x >> 6;
    const int lr = lane & 15;
    const int quad = lane >> 4;
    const int wr = w >> 1, wc = w & 1;
    const int rbase = blockIdx.x * 64;
    const int cbase = blockIdx.y * 128;
    const int dma_r = lane >> 3;
    const int dma_cc = ((lane & 7) ^ dma_r) * 8;

    if (threadIdx.x == 0) sgate = 0;
    __syncthreads();
    const int b_g = rbase >> 11;
    int any = 0;
    for (int i = threadIdx.x; i < LL; i += 256) any |= mask[b_g * LL + i];
    if (any) sgate = 1;   // benign same-value race; barriers below publish

    f4v acc[2][4] = {};
    for (int kt = 0; kt < DD / 64; kt++) {
        const int k0 = kt * 64;
        __syncthreads();
#pragma unroll
        for (int t = 0; t < 2; t++) {
            const int g = w * 2 + t;               // A groups 0..7
            async_cp16(A + (size_t)(rbase + g * 8 + dma_r) * DD + k0 + dma_cc,
                       &sA[g * 512]);
        }
#pragma unroll
        for (int t = 0; t < 4; t++) {
            const int g = w * 4 + t;               // B groups 0..15
            async_cp16(W + (size_t)(cbase + g * 8 + dma_r) * DD + k0 + dma_cc,
                       &sB[g * 512]);
        }
        __syncthreads();   // implicit vmcnt(0) drain -> tile staged
#pragma unroll
        for (int s = 0; s < 2; s++) {
            s8v a[2], b[4];
#pragma unroll
            for (int i = 0; i < 2; i++) {
                const int row = wr * 32 + i * 16 + lr;
                a[i] = *(const s8v*)&sA[row * 64 + (((s * 4 + quad) ^ (row & 7)) * 8)];
            }
#pragma unroll
            for (int j = 0; j < 4; j++) {
                const int row = wc * 64 + j * 16 + lr;
                b[j] = *(const s8v*)&sB[row * 64 + (((s * 4 + quad) ^ (row & 7)) * 8)];
            }
#pragma unroll
            for (int i = 0; i < 2; i++)
#pragma unroll
                for (int j = 0; j < 4; j++)
                    acc[i][j] = __builtin_amdgcn_mfma_f32_16x16x32_bf16(b[j], a[i], acc[i][j], 0, 0, 0);
        }
    }

    const float gatef = sgate ? 1.0f : 0.0f;
    // SWAP layout: m = rbase+wr*32+i*16+lr ; n = cbase+wc*64+j*16+quad*4+r
#pragma unroll
    for (int j = 0; j < 4; j++) {
        const int n = cbase + wc * 64 + j * 16 + quad * 4;
        const f4v bv = *(const f4v*)&bias[n];
#pragma unroll
        for (int i = 0; i < 2; i++) {
            const int m = rbase + wr * 32 + i * 16 + lr;
            float4 o;
            o.x = (acc[i][j][0] + bv[0]) * gatef;
            o.y = (acc[i][j][1] + bv[1]) * gatef;
            o.z = (acc[i][j][2] + bv[2]) * gatef;
            o.w = (acc[i][j][3] + bv[3]) * gatef;
            *(float4*)&out_f[(size_t)m * DD + n] = o;
        }
    }
}

// ---------------------------------------------------------------------------
// Flash attention (round-6 exact source, measured 72.5 us): S^T form,
// log2-domain softmax WITHOUT max tracking; per-lane denominator reduced
// once at the end. Block = (b,h,128q), 8 waves x 16q sharing K/V LDS tiles
// (40 KB LDS, grid 512 = 2 blocks/CU), double-buffered DMA staging.
// Zero-exchange P via permuted K-row loads; s_setprio(1) around MFMA.
// ---------------------------------------------------------------------------
__global__ __launch_bounds__(512) void attn_kernel(const bf16* __restrict__ Q,
                                                   const bf16* __restrict__ K,
                                                   const bf16* __restrict__ Vt,
                                                   const int* __restrict__ mask,
                                                   bf16* __restrict__ Aout) {
    __shared__ bf16 sK[2][64 * 64];    // 16 KB
    __shared__ bf16 sV[2][64 * 64];    // 16 KB
    __shared__ float sBias[LL];        // 8 KB log2-domain additive bias

    const int lane = threadIdx.x & 63;
    const int w = threadIdx.x >> 6;    // 0..7
    const int lr = lane & 15;
    const int quad = lane >> 4;

    const int bid = blockIdx.x;
    const int qb = bid & 15;           // 16 q-blocks of 128
    const int h = (bid >> 4) & 15;
    const int b = bid >> 8;

    const size_t head_off = ((size_t)(b * HH + h)) * LL * HD;
    const bf16* Qh = Q + head_off;
    const bf16* Kh = K + head_off;
    const bf16* Vh = Vt + head_off;    // [HD][LL] per head
    const int q0 = qb * 128 + w * 16;

    const int dma_r = lane >> 3;
    // V staging: store chunk c of row r at position c ^ (r&7)
    const int dma_cv = ((lane & 7) ^ dma_r) * 8;
    // K staging: store chunk c of row r at position c ^ ((r&3)|(((r>>3)&1)<<2))
    // row = w*8 + dma_r -> r&3 = dma_r&3, (r>>3)&1 = w&1
    const int dma_ck = ((lane & 7) ^ ((dma_r & 3) | ((w & 1) << 2))) * 8;

    // prologue: bias fill + stage tile 0 (K and V); wave w stages group w
    {
        const int* mb = mask + b * LL;
        for (int i = threadIdx.x; i < LL; i += 512)
            sBias[i] = mb[i] ? 0.0f : MASK_B2;
        async_cp16(Kh + (size_t)(w * 8 + dma_r) * HD + dma_ck, &sK[0][w * 512]);
        async_cp16(Vh + (size_t)(w * 8 + dma_r) * LL + dma_cv, &sV[0][w * 512]);
    }
    __syncthreads();

    const s8v aq0 = *(const s8v*)(Qh + (size_t)(q0 + lr) * HD + quad * 8);
    const s8v aq1 = *(const s8v*)(Qh + (size_t)(q0 + lr) * HD + 32 + quad * 8);

    f4v O[4] = {};
    float lacc = 0.0f;   // per-lane denominator partial (reduced once at end)

    const int swk = (lr & 3) | (((lr >> 2) & 1) << 2);   // = sK(row(j,lr))
    const int swv = lr & 7;
    const int krow0 = 8 * (lr >> 2) + (lr & 3);

    for (int kt = 0; kt < LL / 64; kt++) {
        const int kbase = kt * 64;
        const bf16* kb = &sK[kt & 1][0];
        const bf16* vb = &sV[kt & 1][0];

        // stage next K+V tile into the other buffer (1 group per wave)
        if (kt < LL / 64 - 1) {
            const int nb = (kt + 1) & 1;
            async_cp16(Kh + (size_t)(kbase + 64 + w * 8 + dma_r) * HD + dma_ck,
                       &sK[nb][w * 512]);
            async_cp16(Vh + (size_t)(w * 8 + dma_r) * LL + kbase + 64 + dma_cv,
                       &sV[nb][w * 512]);
        }

        // T = K Q^T with permuted key rows: T[j][r] at (lr,quad) holds
        // S[key = 32*(j>>1) + 8*quad + 4*(j&1) + r][q = lr]
        f4v T[4];
        __builtin_amdgcn_s_setprio(1);
#pragma unroll
        for (int j = 0; j < 4; j++) {
            const int row = krow0 + 32 * (j >> 1) + 4 * (j & 1);
            const s8v kb0 = *(const s8v*)&kb[row * 64 + ((quad ^ swk) * 8)];
            const s8v kb1 = *(const s8v*)&kb[row * 64 + (((quad + 4) ^ swk) * 8)];
            f4v t = {};
            t = __builtin_amdgcn_mfma_f32_16x16x32_bf16(kb0, aq0, t, 0, 0, 0);
            T[j] = __builtin_amdgcn_mfma_f32_16x16x32_bf16(kb1, aq1, t, 0, 0, 0);
        }
        __builtin_amdgcn_s_setprio(0);

        // V fragments (A-operand of O^T): lane holds V^T[d=dt*16+lr][k]
        s8v v0[4], v1[4];
#pragma unroll
        for (int dt = 0; dt < 4; dt++) {
            const int vrow = dt * 16 + lr;
            v0[dt] = *(const s8v*)&vb[vrow * 64 + ((quad ^ swv) * 8)];
            v1[dt] = *(const s8v*)&vb[vrow * 64 + (((quad + 4) ^ swv) * 8)];
        }

        // P = exp2(S*CSCALE + bias) directly; accumulate per-lane denom
        union { s8v v; bf16 e[8]; } p0, p1;
#pragma unroll
        for (int j = 0; j < 4; j++) {
            const f4v bj = *(const f4v*)&sBias[kbase + 32 * (j >> 1) + 8 * quad + 4 * (j & 1)];
#pragma unroll
            for (int r = 0; r < 4; r++) {
                const float e = exp2f(T[j][r] * CSCALE + bj[r]);
                T[j][r] = e;
                lacc += e;
            }
        }
#pragma unroll
        for (int r = 0; r < 4; r++) {
            p0.e[r]     = __float2bfloat16(T[0][r]);
            p0.e[r + 4] = __float2bfloat16(T[1][r]);
            p1.e[r]     = __float2bfloat16(T[2][r]);
            p1.e[r + 4] = __float2bfloat16(T[3][r]);
        }

        // O^T[d][q] += V^T-frag * P-frag
        __builtin_amdgcn_s_setprio(1);
#pragma unroll
        for (int dt = 0; dt < 4; dt++) {
            O[dt] = __builtin_amdgcn_mfma_f32_16x16x32_bf16(v0[dt], p0.v, O[dt], 0, 0, 0);
            O[dt] = __builtin_amdgcn_mfma_f32_16x16x32_bf16(v1[dt], p1.v, O[dt], 0, 0, 0);
        }
        __builtin_amdgcn_s_setprio(0);

        __syncthreads();   // buffer handoff (drains next-tile DMA)
    }

    // reduce denominator once: lanes {lr, lr+16, lr+32, lr+48} cover all keys
    float lt = lacc;
    lt += __shfl_xor(lt, 16);
    lt += __shfl_xor(lt, 32);
    const float linv = (lt > 0.0f) ? (1.0f / lt) : 0.0f;

    // O^T lane holds q = lr, d = dt*16 + quad*4 + r -> direct 8B stores
#pragma unroll
    for (int dt = 0; dt < 4; dt++) {
        B4 o;
#pragma unroll
        for (int r = 0; r < 4; r++) o.v[r] = __float2bfloat16(O[dt][r] * linv);
        *(B4*)&Aout[((size_t)(b * LL + q0 + lr)) * DD + h * HD + dt * 16 + quad * 4] = o;
    }
}

// ---------------------------------------------------------------------------
extern "C" void kernel_launch(void* const* d_in, const int* in_sizes, int n_in,
                              void* d_out, int out_size, void* d_ws, size_t ws_size,
                              hipStream_t stream) {
    const float* query = (const float*)d_in[0];
    const float* key   = (const float*)d_in[1];
    const float* value = (const float*)d_in[2];
    const float* Wq = (const float*)d_in[3];
    const float* bq = (const float*)d_in[4];
    const float* Wk = (const float*)d_in[5];
    const float* bk = (const float*)d_in[6];
    const float* Wv = (const float*)d_in[7];
    const float* bv = (const float*)d_in[8];
    const float* Wo = (const float*)d_in[9];
    const float* bo = (const float*)d_in[10];
    const int* mask = (const int*)d_in[11];

    bf16* base = (bf16*)d_ws;
    bf16* qx = base;
    bf16* kx = qx + PER_T;
    bf16* vx = kx + PER_T;
    bf16* wq = vx + PER_T;
    bf16* wk = wq + DD * DD;
    bf16* wv = wk + DD * DD;
    bf16* wo = wv + DD * DD;
    bf16* Qs = wo + DD * DD;
    bf16* Ks = Qs + PER_T;
    bf16* Vst = Ks + PER_T;
    bf16* aws = Vst + PER_T;

    CvtArgs ca;
    ca.src[0] = query; ca.dst[0] = qx; ca.n[0] = PER_T;
    ca.src[1] = key;   ca.dst[1] = kx; ca.n[1] = PER_T;
    ca.src[2] = value; ca.dst[2] = vx; ca.n[2] = PER_T;
    ca.src[3] = Wq;    ca.dst[3] = wq; ca.n[3] = DD * DD;
    ca.src[4] = Wk;    ca.dst[4] = wk; ca.n[4] = DD * DD;
    ca.src[5] = Wv;    ca.dst[5] = wv; ca.n[5] = DD * DD;
    ca.src[6] = Wo;    ca.dst[6] = wo; ca.n[6] = DD * DD;
    cvt_kernel<<<dim3(1024, 7), 256, 0, stream>>>(ca);

    QkvArgs qa;
    qa.A[0] = qx; qa.W[0] = wq; qa.bias[0] = bq; qa.out[0] = Qs;
    qa.A[1] = kx; qa.W[1] = wk; qa.bias[1] = bk; qa.out[1] = Ks;
    qa.A[2] = vx; qa.W[2] = wv; qa.bias[2] = bv; qa.out[2] = Vst;

    // fused Q/K/V projections: 32 x 8 x 3 = 768 blocks (~3/CU)
    gemm128<<<dim3(MTOT / 128, DD / 128, 3), 256, 0, stream>>>(qa);

    // 8-wave blocks of 128 q (16 q per wave): 2*16*16 = 512 blocks, 2/CU
    attn_kernel<<<BB * HH * (LL / 128), 512, 0, stream>>>(Qs, Ks, Vst, mask, aws);

    // O-projection: 64x128 tiles -> 64 x 8 = 512 blocks = 2/CU, 8 waves/CU
    oproj64<<<dim3(MTOT / 64, DD / 128), 256, 0, stream>>>(
        aws, wo, bo, (float*)d_out, mask);
}